// Round 4
// baseline (320.299 us; speedup 1.0000x reference)
//
#include <hip/hip_runtime.h>
#include <hip/hip_bf16.h>
#include <math.h>

#define N 8192
#define D 256
#define MARGIN 0.3f
#define EPS 1e-12f

#define BT 128                             // block tile (i and j)
#define BK 64                              // K chunk staged in LDS
#define NJB (N / BT)                       // 64 tile-blocks per dim
#define TOTAL_TRI (NJB * (NJB + 1) / 2)    // 2080 working blocks

typedef __attribute__((ext_vector_type(8))) short short8;   // 8 bf16 in 4 VGPRs
typedef __attribute__((ext_vector_type(4))) float floatx4;  // MFMA C/D

static __device__ inline ushort f2bf(float f) {
    __hip_bfloat16 h = __float2bfloat16(f);
    return *reinterpret_cast<ushort*>(&h);
}

// async global->LDS, 16B per lane, dest = wave-uniform base + lane*16
static __device__ inline void gload_lds16(const void* g, void* l) {
    __builtin_amdgcn_global_load_lds((const __attribute__((address_space(1))) unsigned int*)g,
                                     (__attribute__((address_space(3))) unsigned int*)l,
                                     16, 0, 0);
}

// order-preserving float <-> uint key (no NaNs in data)
static __device__ inline unsigned fkey(float f) {
    unsigned b = __float_as_uint(f);
    return (b & 0x80000000u) ? ~b : (b | 0x80000000u);
}
static __device__ inline float unkey(unsigned k) {
    return __uint_as_float((k & 0x80000000u) ? (k ^ 0x80000000u) : ~k);
}

// ---------------- Kernel 1: L2 normalize rows -> bf16 copy; init keys + counter ----------------
__global__ __launch_bounds__(256) void normalize_kernel(const float* __restrict__ x,
                                                        ushort* __restrict__ fn16,
                                                        unsigned* __restrict__ gp_key,
                                                        unsigned* __restrict__ gn_key,
                                                        unsigned* __restrict__ counter) {
    const int gid = blockIdx.x * 256 + threadIdx.x;
    if (gid < N) { gp_key[gid] = 0xFFFFFFFFu; gn_key[gid] = 0u; }  // min/max identities
    if (gid == 0) counter[0] = 0u;

    const int row  = blockIdx.x * 4 + (threadIdx.x >> 6);   // 1 wave per row
    const int lane = threadIdx.x & 63;
    float4 v = ((const float4*)(x + (size_t)row * D))[lane];
    float s = v.x * v.x + v.y * v.y + v.z * v.z + v.w * v.w;
    #pragma unroll
    for (int off = 32; off; off >>= 1) s += __shfl_down(s, off);
    s = __shfl(s, 0);
    const float inv = 1.0f / fmaxf(sqrtf(s), 1e-12f);
    ushort4 b;
    b.x = f2bf(v.x * inv); b.y = f2bf(v.y * inv);
    b.z = f2bf(v.z * inv); b.w = f2bf(v.w * inv);
    ((ushort4*)(fn16 + (size_t)row * D))[lane] = b;
}

// ---------------- Kernel 2: triangular bf16 MFMA gram + batch-hard on g + last-block finish ----
// Upper-triangle tiles only (jb >= ib). Column reduction of tile (ib,jb) covers rows j (split ib);
// row reduction (off-diagonal only) covers rows i (split jb). Reductions run on g (d2 = 2 - 2g,
// monotone decreasing; ||f||^2 == 1 to ~1e-6 post-normalization). Partials merge via device-scope
// atomicMin/Max on order-preserving uint keys; last block computes the final loss.
__global__ __launch_bounds__(256, 4) void gram_kernel(const ushort* __restrict__ fn16,
                                                      const int* __restrict__ lab,
                                                      unsigned* __restrict__ gp_key,
                                                      unsigned* __restrict__ gn_key,
                                                      unsigned* __restrict__ counter,
                                                      float* __restrict__ out) {
    __shared__ ushort As[BT][BK];     // 16 KB, XOR-swizzled chunks
    __shared__ ushort Bs[BT][BK];     // 16 KB
    __shared__ float cGp[BT][2], cGn[BT][2];   // column partials, per wi half
    __shared__ float rGp[BT][2], rGn[BT][2];   // row partials, per wj half
    __shared__ int lastFlag;
    __shared__ float wsum[4];

    const int jb = blockIdx.x, ib = blockIdx.y;
    if (jb < ib) return;                        // lower triangle: exit immediately
    const bool offdiag = (jb > ib);
    const int i0 = ib * BT, j0 = jb * BT;

    const int t    = threadIdx.x;
    const int w    = t >> 6;
    const int lane = t & 63;
    const int wi   = w >> 1, wj = w & 1;        // 2x2 waves, each 64x64
    const int quad = lane >> 4;
    const int l15  = lane & 15;

    floatx4 acc[4][4];
    #pragma unroll
    for (int m = 0; m < 4; m++)
        #pragma unroll
        for (int n = 0; n < 4; n++)
            acc[m][n] = (floatx4){0.f, 0.f, 0.f, 0.f};

    for (int kc = 0; kc < D; kc += BK) {
        __syncthreads();
        #pragma unroll
        for (int q = 0; q < 4; q++) {
            const int s  = q * 256 + w * 64 + lane;
            const int r  = s >> 3;
            const int cl = (s & 7) ^ (r & 7);          // logical chunk for this phys slot
            const int base = (q * 256 + w * 64) * 8;
            gload_lds16(fn16 + (size_t)(i0 + r) * D + kc + cl * 8, (ushort*)As + base);
            gload_lds16(fn16 + (size_t)(j0 + r) * D + kc + cl * 8, (ushort*)Bs + base);
        }
        __syncthreads();
        #pragma unroll
        for (int ks = 0; ks < 2; ks++) {
            short8 af[4], bf_[4];
            #pragma unroll
            for (int m = 0; m < 4; m++) {
                const int rr = wi * 64 + m * 16 + l15;
                const int cp = (ks * 4 + quad) ^ (rr & 7);
                af[m] = *(const short8*)(&As[rr][cp * 8]);
            }
            #pragma unroll
            for (int n = 0; n < 4; n++) {
                const int rr = wj * 64 + n * 16 + l15;
                const int cp = (ks * 4 + quad) ^ (rr & 7);
                bf_[n] = *(const short8*)(&Bs[rr][cp * 8]);
            }
            #pragma unroll
            for (int m = 0; m < 4; m++)
                #pragma unroll
                for (int n = 0; n < 4; n++)
                    acc[m][n] = __builtin_amdgcn_mfma_f32_16x16x32_bf16(af[m], bf_[n], acc[m][n], 0, 0, 0);
        }
    }

    // ---- epilogue on g. C/D layout: col = l15 (tile col n*16+l15), row = quad*4 + reg.
    int labj[4];
    #pragma unroll
    for (int n = 0; n < 4; n++) labj[n] = lab[j0 + wj * 64 + n * 16 + l15];
    float gpc[4], gnc[4];
    #pragma unroll
    for (int n = 0; n < 4; n++) { gpc[n] = INFINITY; gnc[n] = -INFINITY; }

    #pragma unroll
    for (int m = 0; m < 4; m++) {
        #pragma unroll
        for (int r = 0; r < 4; r++) {
            const int irow = wi * 64 + m * 16 + quad * 4 + r;
            const int labi = lab[i0 + irow];
            float pr = INFINITY, nr = -INFINITY;
            #pragma unroll
            for (int n = 0; n < 4; n++) {
                const float g = acc[m][n][r];
                const bool same = (labi == labj[n]);
                const float selp = same ? g : INFINITY;
                const float seln = same ? -INFINITY : g;
                pr = fminf(pr, selp);           nr = fmaxf(nr, seln);
                gpc[n] = fminf(gpc[n], selp);   gnc[n] = fmaxf(gnc[n], seln);
            }
            if (offdiag) {                      // row-side: reduce across 16 cols (l15 lanes)
                #pragma unroll
                for (int o = 1; o < 16; o <<= 1) {
                    pr = fminf(pr, __shfl_xor(pr, o));
                    nr = fmaxf(nr, __shfl_xor(nr, o));
                }
                if (l15 == 0) { rGp[irow][wj] = pr; rGn[irow][wj] = nr; }
            }
        }
    }
    // column-side: reduce across 4 quads (rows of wi half)
    #pragma unroll
    for (int n = 0; n < 4; n++) {
        float p = gpc[n], q2 = gnc[n];
        p  = fminf(p,  __shfl_xor(p, 16));  p  = fminf(p,  __shfl_xor(p, 32));
        q2 = fmaxf(q2, __shfl_xor(q2, 16)); q2 = fmaxf(q2, __shfl_xor(q2, 32));
        if (quad == 0) {
            const int col = wj * 64 + n * 16 + l15;
            cGp[col][wi] = p; cGn[col][wi] = q2;
        }
    }
    __syncthreads();
    if (t < BT) {
        atomicMin(&gp_key[j0 + t], fkey(fminf(cGp[t][0], cGp[t][1])));
        atomicMax(&gn_key[j0 + t], fkey(fmaxf(cGn[t][0], cGn[t][1])));
        if (offdiag) {
            atomicMin(&gp_key[i0 + t], fkey(fminf(rGp[t][0], rGp[t][1])));
            atomicMax(&gn_key[i0 + t], fkey(fmaxf(rGn[t][0], rGn[t][1])));
        }
    }

    // ---- completion: last working block computes the loss
    __threadfence();
    if (t == 0) lastFlag = (atomicAdd(counter, 1u) == (unsigned)(TOTAL_TRI - 1)) ? 1 : 0;
    __syncthreads();
    if (lastFlag) {
        __threadfence();
        float sum = 0.f;
        for (int i = t; i < N; i += 256) {
            const unsigned kp = __hip_atomic_load(&gp_key[i], __ATOMIC_RELAXED, __HIP_MEMORY_SCOPE_AGENT);
            const unsigned kn = __hip_atomic_load(&gn_key[i], __ATOMIC_RELAXED, __HIP_MEMORY_SCOPE_AGENT);
            const float gp = unkey(kp), gn = unkey(kn);
            const float dp = sqrtf(fmaxf(2.0f - 2.0f * gp, EPS));  // hardest_pos dist
            const float dn = sqrtf(fmaxf(2.0f - 2.0f * gn, EPS));  // hardest_neg dist
            const float l = dp - dn + MARGIN;
            sum += (l > 0.f) ? l : 0.f;
        }
        #pragma unroll
        for (int off = 32; off; off >>= 1) sum += __shfl_down(sum, off);
        if (lane == 0) wsum[w] = sum;
        __syncthreads();
        if (t == 0) out[0] = (wsum[0] + wsum[1] + wsum[2] + wsum[3]) * (1.0f / (float)N);
    }
}

extern "C" void kernel_launch(void* const* d_in, const int* in_sizes, int n_in,
                              void* d_out, int out_size, void* d_ws, size_t ws_size,
                              hipStream_t stream) {
    const float* x   = (const float*)d_in[0];
    const int*   lab = (const int*)d_in[1];
    float* out = (float*)d_out;

    char* ws = (char*)d_ws;
    ushort*   fn16    = (ushort*)ws;                                    // N*D bf16 = 4 MB
    unsigned* gp_key  = (unsigned*)(ws + (size_t)N * D * 2);            // N uints
    unsigned* gn_key  = gp_key + N;                                     // N uints
    unsigned* counter = gn_key + N;                                     // 1 uint

    normalize_kernel<<<N / 4, 256, 0, stream>>>(x, fn16, gp_key, gn_key, counter);
    dim3 grid(NJB, NJB);
    gram_kernel<<<grid, 256, 0, stream>>>(fn16, lab, gp_key, gn_key, counter, out);
}

// Round 5
// 122.027 us; speedup vs baseline: 2.6248x; 2.6248x over previous
//
#include <hip/hip_runtime.h>
#include <hip/hip_bf16.h>
#include <math.h>

#define N 8192
#define D 256
#define MARGIN 0.3f
#define EPS 1e-12f

#define BT 128                             // block tile (i and j)
#define BK 64                              // K chunk staged in LDS
#define NJB (N / BT)                       // 64 tile-blocks per dim
#define TOTAL_TRI (NJB * (NJB + 1) / 2)    // 2080 upper-triangle tiles

typedef __attribute__((ext_vector_type(8))) short short8;   // 8 bf16 in 4 VGPRs
typedef __attribute__((ext_vector_type(4))) float floatx4;  // MFMA C/D

static __device__ inline ushort f2bf(float f) {
    __hip_bfloat16 h = __float2bfloat16(f);
    return *reinterpret_cast<ushort*>(&h);
}

// async global->LDS, 16B per lane, dest = wave-uniform base + lane*16
static __device__ inline void gload_lds16(const void* g, void* l) {
    __builtin_amdgcn_global_load_lds((const __attribute__((address_space(1))) unsigned int*)g,
                                     (__attribute__((address_space(3))) unsigned int*)l,
                                     16, 0, 0);
}

// ---------------- Kernel 1: L2 normalize rows -> bf16 copy; zero the output ----------------
__global__ __launch_bounds__(256) void normalize_kernel(const float* __restrict__ x,
                                                        ushort* __restrict__ fn16,
                                                        float* __restrict__ out) {
    if (blockIdx.x == 0 && threadIdx.x == 0) out[0] = 0.0f;
    const int row  = blockIdx.x * 4 + (threadIdx.x >> 6);   // 1 wave per row
    const int lane = threadIdx.x & 63;
    float4 v = ((const float4*)(x + (size_t)row * D))[lane];
    float s = v.x * v.x + v.y * v.y + v.z * v.z + v.w * v.w;
    #pragma unroll
    for (int off = 32; off; off >>= 1) s += __shfl_down(s, off);
    s = __shfl(s, 0);
    const float inv = 1.0f / fmaxf(sqrtf(s), 1e-12f);
    ushort4 b;
    b.x = f2bf(v.x * inv); b.y = f2bf(v.y * inv);
    b.z = f2bf(v.z * inv); b.w = f2bf(v.w * inv);
    ((ushort4*)(fn16 + (size_t)row * D))[lane] = b;
}

// ---------------- Kernel 2: triangular bf16 MFMA gram + batch-hard partials on g -------------
// Upper-triangle tiles only (jb >= ib). Reductions run on g (post-norm ||f||^2 == 1, d2 = 2-2g,
// monotone decreasing: hardest_pos = min g over positives, hardest_neg = max g over negatives).
// Tile (ib,jb): column-side partials (over the 128 i-rows, per j-column) -> slot ib, rows j;
// off-diag row-side partials (over the 128 j-cols, per i-row) -> slot jb, rows i.
// Every (slot, row) pair is written exactly once: plain stores, no atomics, no fences.
__global__ __launch_bounds__(256, 4) void gram_kernel(const ushort* __restrict__ fn16,
                                                      const int* __restrict__ lab,
                                                      float* __restrict__ gp_part,
                                                      float* __restrict__ gn_part) {
    __shared__ ushort As[BT][BK];     // 16 KB, XOR-swizzled chunks
    __shared__ ushort Bs[BT][BK];     // 16 KB
    __shared__ float cGp[BT][2], cGn[BT][2];   // column partials, per wi half
    __shared__ float rGp[BT][2], rGn[BT][2];   // row partials, per wj half

    // triangular decode: idx -> (ib, jb), row-major over jb >= ib
    const int idx = blockIdx.x;
    const float c = 2.0f * NJB + 1.0f;
    int ib = (int)((c - sqrtf(c * c - 8.0f * (float)idx)) * 0.5f);
    while (ib > 0 && idx < ib * NJB - ib * (ib - 1) / 2) ib--;
    while (idx >= (ib + 1) * NJB - (ib + 1) * ib / 2) ib++;
    const int jb = ib + (idx - (ib * NJB - ib * (ib - 1) / 2));
    const bool offdiag = (jb > ib);
    const int i0 = ib * BT, j0 = jb * BT;

    const int t    = threadIdx.x;
    const int w    = t >> 6;
    const int lane = t & 63;
    const int wi   = w >> 1, wj = w & 1;        // 2x2 waves, each 64x64
    const int quad = lane >> 4;
    const int l15  = lane & 15;

    floatx4 acc[4][4];
    #pragma unroll
    for (int m = 0; m < 4; m++)
        #pragma unroll
        for (int n = 0; n < 4; n++)
            acc[m][n] = (floatx4){0.f, 0.f, 0.f, 0.f};

    const ushort (*Bsrc)[BK] = offdiag ? Bs : As;   // diagonal tile: B == A

    for (int kc = 0; kc < D; kc += BK) {
        __syncthreads();
        #pragma unroll
        for (int q = 0; q < 4; q++) {
            const int s  = q * 256 + w * 64 + lane;
            const int r  = s >> 3;
            const int cl = (s & 7) ^ (r & 7);          // logical chunk for this phys slot
            const int base = (q * 256 + w * 64) * 8;
            gload_lds16(fn16 + (size_t)(i0 + r) * D + kc + cl * 8, (ushort*)As + base);
            if (offdiag)
                gload_lds16(fn16 + (size_t)(j0 + r) * D + kc + cl * 8, (ushort*)Bs + base);
        }
        __syncthreads();
        #pragma unroll
        for (int ks = 0; ks < 2; ks++) {
            short8 af[4], bf_[4];
            #pragma unroll
            for (int m = 0; m < 4; m++) {
                const int rr = wi * 64 + m * 16 + l15;
                const int cp = (ks * 4 + quad) ^ (rr & 7);
                af[m] = *(const short8*)(&As[rr][cp * 8]);
            }
            #pragma unroll
            for (int n = 0; n < 4; n++) {
                const int rr = wj * 64 + n * 16 + l15;
                const int cp = (ks * 4 + quad) ^ (rr & 7);
                bf_[n] = *(const short8*)(&Bsrc[rr][cp * 8]);
            }
            #pragma unroll
            for (int m = 0; m < 4; m++)
                #pragma unroll
                for (int n = 0; n < 4; n++)
                    acc[m][n] = __builtin_amdgcn_mfma_f32_16x16x32_bf16(af[m], bf_[n], acc[m][n], 0, 0, 0);
        }
    }

    // ---- epilogue on g. C/D layout: col = l15 (tile col wj*64+n*16+l15), row = quad*4 + reg.
    int labj[4];
    #pragma unroll
    for (int n = 0; n < 4; n++) labj[n] = lab[j0 + wj * 64 + n * 16 + l15];
    float gpc[4], gnc[4];
    #pragma unroll
    for (int n = 0; n < 4; n++) { gpc[n] = INFINITY; gnc[n] = -INFINITY; }

    #pragma unroll
    for (int m = 0; m < 4; m++) {
        #pragma unroll
        for (int r = 0; r < 4; r++) {
            const int irow = wi * 64 + m * 16 + quad * 4 + r;
            const int labi = lab[i0 + irow];
            float pr = INFINITY, nr = -INFINITY;
            #pragma unroll
            for (int n = 0; n < 4; n++) {
                const float g = acc[m][n][r];
                const bool same = (labi == labj[n]);
                const float selp = same ? g : INFINITY;
                const float seln = same ? -INFINITY : g;
                pr = fminf(pr, selp);           nr = fmaxf(nr, seln);
                gpc[n] = fminf(gpc[n], selp);   gnc[n] = fmaxf(gnc[n], seln);
            }
            if (offdiag) {                      // row-side: reduce across 16 cols (l15 lanes)
                #pragma unroll
                for (int o = 1; o < 16; o <<= 1) {
                    pr = fminf(pr, __shfl_xor(pr, o));
                    nr = fmaxf(nr, __shfl_xor(nr, o));
                }
                if (l15 == 0) { rGp[irow][wj] = pr; rGn[irow][wj] = nr; }
            }
        }
    }
    // column-side: reduce across 4 quads (covers all 64 rows of the wi half)
    #pragma unroll
    for (int n = 0; n < 4; n++) {
        float p = gpc[n], q2 = gnc[n];
        p  = fminf(p,  __shfl_xor(p, 16));  p  = fminf(p,  __shfl_xor(p, 32));
        q2 = fmaxf(q2, __shfl_xor(q2, 16)); q2 = fmaxf(q2, __shfl_xor(q2, 32));
        if (quad == 0) {
            const int col = wj * 64 + n * 16 + l15;
            cGp[col][wi] = p; cGn[col][wi] = q2;
        }
    }
    __syncthreads();
    if (t < BT) {
        gp_part[(size_t)ib * N + j0 + t] = fminf(cGp[t][0], cGp[t][1]);
        gn_part[(size_t)ib * N + j0 + t] = fmaxf(cGn[t][0], cGn[t][1]);
        if (offdiag) {
            gp_part[(size_t)jb * N + i0 + t] = fminf(rGp[t][0], rGp[t][1]);
            gn_part[(size_t)jb * N + i0 + t] = fmaxf(rGn[t][0], rGn[t][1]);
        }
    }
}

// ---------------- Kernel 3: fold slots, sqrt, relu, mean (one atomic per block) --------------
__global__ __launch_bounds__(256) void reduce_kernel(const float* __restrict__ gp_part,
                                                     const float* __restrict__ gn_part,
                                                     float* __restrict__ out) {
    const int i = blockIdx.x * 256 + threadIdx.x;   // 32 blocks x 256 = 8192 rows
    float gp = INFINITY, gn = -INFINITY;
    for (int s = 0; s < NJB; s++) {
        gp = fminf(gp, gp_part[(size_t)s * N + i]);
        gn = fmaxf(gn, gn_part[(size_t)s * N + i]);
    }
    const float dp = sqrtf(fmaxf(2.0f - 2.0f * gp, EPS));  // hardest_pos distance
    const float dn = sqrtf(fmaxf(2.0f - 2.0f * gn, EPS));  // hardest_neg distance
    const float l  = dp - dn + MARGIN;
    float sum = (l > 0.0f) ? l : 0.0f;
    #pragma unroll
    for (int off = 32; off; off >>= 1) sum += __shfl_down(sum, off);
    __shared__ float wsum[4];
    if ((threadIdx.x & 63) == 0) wsum[threadIdx.x >> 6] = sum;
    __syncthreads();
    if (threadIdx.x == 0)
        atomicAdd(out, (wsum[0] + wsum[1] + wsum[2] + wsum[3]) * (1.0f / (float)N));
}

extern "C" void kernel_launch(void* const* d_in, const int* in_sizes, int n_in,
                              void* d_out, int out_size, void* d_ws, size_t ws_size,
                              hipStream_t stream) {
    const float* x   = (const float*)d_in[0];
    const int*   lab = (const int*)d_in[1];
    float* out = (float*)d_out;

    char* ws = (char*)d_ws;
    ushort* fn16    = (ushort*)ws;                                  // N*D bf16 = 4 MB
    float*  gp_part = (float*)(ws + (size_t)N * D * 2);             // NJB*N floats = 2 MB
    float*  gn_part = gp_part + (size_t)NJB * N;                    // NJB*N floats = 2 MB

    normalize_kernel<<<N / 4, 256, 0, stream>>>(x, fn16, out);
    gram_kernel<<<TOTAL_TRI, 256, 0, stream>>>(fn16, lab, gp_part, gn_part);
    reduce_kernel<<<N / 256, 256, 0, stream>>>(gp_part, gn_part, out);
}